// Round 13
// baseline (138.272 us; speedup 1.0000x reference)
//
#include <hip/hip_runtime.h>

typedef __attribute__((ext_vector_type(8))) short short8;
typedef __attribute__((ext_vector_type(8))) _Float16 half8;
typedef __attribute__((ext_vector_type(4))) float float4v;
typedef __attribute__((ext_vector_type(16))) float float16v;

#define SDIM 64

// output tensor offsets (floats)
#define MU_OFF   0
#define COV_OFF  1536000
#define OP_OFF   4608000
#define SH_OFF   5120000

// barrier with LDS-only drain: keeps global loads (prefetch/gathers) in flight
#define BARRIER_LGKM() asm volatile("s_waitcnt lgkmcnt(0)\n\ts_barrier" ::: "memory")

__device__ __forceinline__ unsigned short f2h(float f){
  _Float16 h = (_Float16)f;                 // v_cvt_f16_f32 (RNE)
  return *(unsigned short*)&h;
}
__device__ __forceinline__ float h2f(unsigned short u){
  _Float16 h = *(_Float16*)&u; return (float)h;
}
// packed fp16: r = max(p + e, 0)  (2 VALU ops per 2 elements)
__device__ __forceinline__ unsigned pk_relu_add_f16(unsigned p, unsigned e, unsigned z){
  unsigned r;
  asm("v_pk_add_f16 %0, %1, %2\n\tv_pk_max_f16 %0, %0, %3"
      : "=&v"(r) : "v"(p), "v"(e), "v"(z));
  return r;
}
// pack 2 f32 -> 2 f16 (RTZ), single instruction
__device__ __forceinline__ unsigned cvt_pk_f16(float lo, float hi){
  unsigned r; asm("v_cvt_pkrtz_f16_f32 %0, %1, %2" : "=v"(r) : "v"(lo), "v"(hi)); return r;
}

// ---------------- prep: fp16 conversions + pt_part ----------------
__global__ __launch_bounds__(256) void kprep(
    const float* __restrict__ se_w1, const float* __restrict__ gep_w2,
    const float* __restrict__ gep_w3, const float* __restrict__ gep_w1,
    const float* __restrict__ cpts,
    unsigned short* __restrict__ w1b, unsigned short* __restrict__ w2t,
    unsigned short* __restrict__ w3p, unsigned short* __restrict__ ptb){
  int idx = blockIdx.x*256 + threadIdx.x;
  if (idx < 262144){ w1b[idx] = f2h(se_w1[idx]); return; }
  int i1 = idx - 262144;
  if (i1 < 65536){ int n = i1 >> 8, k = i1 & 255; w2t[i1] = f2h(gep_w2[k*256+n]); return; }
  int i2 = idx - 327680;
  if (i2 < 8192){ int j = i2 >> 8, k = i2 & 255; w3p[i2] = f2h(j < 19 ? gep_w3[k*19+j] : 0.f); return; }
  int i3 = idx - 335872;
  if (i3 < 256000){ int p = i3 >> 8, k = i3 & 255;
    float v = cpts[p*3+0]*gep_w1[(SDIM+0)*256+k]
            + cpts[p*3+1]*gep_w1[(SDIM+1)*256+k]
            + cpts[p*3+2]*gep_w1[(SDIM+2)*256+k];
    ptb[i3] = f2h(v);
  }
}

// ---------------- main: fused entity prologue + per-entity point MLP via MFMA ----------------
// 512 threads = 8 waves; wave owns 32 GEMM1 cols. VGPR <=128 for 2 blocks/CU.
// fp16 path, 4 barriers/chunk (disjoint h2H kills the WB1 WAR barrier).
// s_setprio(1) around MFMA clusters: P2b and P4 are role-diverse (T5 prerequisite).
__global__ __launch_bounds__(512, 2) void kmain(
    const float* __restrict__ ef, const int* __restrict__ cls_lab,
    const unsigned short* __restrict__ w1b,
    const float* __restrict__ se_b1, const float* __restrict__ se_gamma,
    const float* __restrict__ se_beta, const float* __restrict__ se_w2,
    const float* __restrict__ se_b2,
    const float* __restrict__ gep_w1, const float* __restrict__ gep_b1,
    const unsigned short* __restrict__ ptb, const unsigned short* __restrict__ w2t,
    const unsigned short* __restrict__ w3p,
    const float* __restrict__ gep_b2, const float* __restrict__ gep_b3,
    const int* __restrict__ adapter_ids,
    const float* __restrict__ mu_tab, const float* __restrict__ cov_tab,
    const float* __restrict__ op_tab, const float* __restrict__ sh_tab,
    float* __restrict__ out){
  __shared__ unsigned short h1L[64*256];   // 32KB, XOR-swizzled rows of 512B (h1; rows 0-31 reused for h2 lo)
  __shared__ unsigned short h2H[32*256];   // 16KB, h2 rows 32-63 (disjoint from h1L -> no WAR barrier)
  __shared__ unsigned short w3L[32*256];   // 16KB (prologue: f32 scratch)
  __shared__ float entL[256];
  __shared__ float b2L[256];
  __shared__ float b3L[32];
  __shared__ float pL[2][64][21];          // double-buffered param staging
  int e = blockIdx.x, t = threadIdx.x;
  int lane = t & 63, wid = t >> 6;        // wid 0..7
  int l32 = lane & 31, hi = lane >> 5;

  // ================= fused entity prologue =================
  {
    float* efF = (float*)h1L;              // [0..1023] ef
    float* red = (float*)h1L + 1024;       // [16][256] matvec partials
    float* scr = (float*)w3L;              // [512..767] hr, [768..1279] styR,
                                           // [1280..1343] styL, [1344..1359] red8
    ((float2*)efF)[t] = ((const float2*)(ef + (size_t)e*1024))[t];
    if (t < 256) b2L[t] = gep_b2[t];
    if (t < 32) b3L[t] = (t < 19) ? gep_b3[t] : 0.f;
    __syncthreads();
    {
      int kg = t >> 5, c8 = (t & 31)*8;
      const unsigned short* wrow = w1b + (kg*64)*256 + c8;
      float a[8];
      #pragma unroll
      for (int j=0;j<8;j++) a[j]=0.f;
      #pragma unroll 8
      for (int k=0;k<64;k++){
        short8 w = *(const short8*)(wrow + k*256);
        float ev = efF[kg*64 + k];
        #pragma unroll
        for (int j=0;j<8;j++) a[j] += ev * h2f((unsigned short)w[j]);
      }
      #pragma unroll
      for (int j=0;j<8;j++) red[kg*256 + c8 + j] = a[j];
    }
    __syncthreads();
    float h = 0.f;
    if (t < 256){
      float s = 0.f;
      #pragma unroll
      for (int g=0; g<16; g++) s += red[g*256 + t];
      h = s + se_b1[t];
    }
    float s1 = h, s2 = h*h;
    #pragma unroll
    for (int o=32;o>0;o>>=1){ s1 += __shfl_xor(s1,o,64); s2 += __shfl_xor(s2,o,64); }
    if (lane==0){ scr[1344+wid]=s1; scr[1352+wid]=s2; }
    __syncthreads();
    float S1=0.f, S2=0.f;
    #pragma unroll
    for (int i=0;i<8;i++){ S1 += scr[1344+i]; S2 += scr[1352+i]; }
    float mean = S1*(1.f/256.f);
    float var  = S2*(1.f/256.f) - mean*mean;
    if (t < 256){
      float hn = (h-mean)*rsqrtf(var+1e-5f)*se_gamma[t] + se_beta[t];
      scr[512+t] = fmaxf(hn, 0.f);
    }
    __syncthreads();
    {
      int s = t & 63, q = t >> 6;
      float st = 0.f;
      #pragma unroll 4
      for (int k=q*32;k<q*32+32;k++) st += scr[512+k]*se_w2[k*64+s];
      scr[768 + q*64 + s] = st;
    }
    __syncthreads();
    if (t < 64){
      float v = 0.f;
      #pragma unroll
      for (int q=0;q<8;q++) v += scr[768 + q*64 + t];
      scr[1280+t] = v + se_b2[t];
    }
    __syncthreads();
    if (t < 256){
      int c = cls_lab[e];
      float ep = gep_b1[t] + gep_w1[(SDIM+3+c)*256 + t];
      #pragma unroll 8
      for (int k=0;k<64;k++) ep += scr[1280+k]*gep_w1[k*256+t];
      entL[t] = ep;
    }
    __syncthreads();                       // scr (w3L), h1L free from here
  }

  // stage W3 padded [32][256] f16 into LDS, swizzled
  #pragma unroll
  for (int i=0;i<2;i++){
    int g = t + i*512; int row = g>>5; int kg = g&31;
    uint4 v = *(const uint4*)(w3p + row*256 + kg*8);
    int bo = (row*512 + kg*16) ^ ((row&7)<<4);
    *(uint4*)((char*)w3L + bo) = v;
  }
  // persistent W2 fragments for 32x32x16 f16 GEMM1: 16 half8 = 64 VGPR
  half8 bB[16];
  #pragma unroll
  for (int s=0;s<16;s++)
    bB[s] = *(const half8*)(w2t + (wid*32 + l32)*256 + s*16 + hi*8);
  __syncthreads();

  int aid = adapter_ids[e];
  const float* muT  = mu_tab  + (size_t)aid*3000;
  const float* covT = cov_tab + (size_t)aid*6000;
  const float* opT  = op_tab  + (size_t)aid*1000;
  const float* shT  = sh_tab  + (size_t)aid*9000;
  int kg0 = (t & 31)*8;
  // ent packed to f16 pairs once (RNE)
  unsigned er_pk[4];
  #pragma unroll
  for (int j=0;j<4;j++)
    er_pk[j] = (unsigned)f2h(entL[kg0+2*j]) | ((unsigned)f2h(entL[kg0+2*j+1])<<16);
  unsigned zero_pk = 0;

  // initial ptb prefetch (chunk 0)
  uint4 pv[4];
  #pragma unroll
  for (int i=0;i<4;i++){
    int p = (t>>5) + i*16;
    pv[i] = *(const uint4*)(ptb + p*256 + (t&31)*8);
  }

  float tmu=0.f, tcov=0.f, top=0.f, tsh0=0.f, tsh1=0.f;   // gathers for chunk c-1

  for (int c=0;c<16;c++){
    int p0 = c*64;
    // ---- P1a: build h1 rows 0-31 (packed f16: 2 VALU per pair) ----
    #pragma unroll
    for (int i=0;i<2;i++){
      int row = (t>>5) + i*16;
      unsigned rw0 = pk_relu_add_f16(pv[i].x, er_pk[0], zero_pk);
      unsigned rw1 = pk_relu_add_f16(pv[i].y, er_pk[1], zero_pk);
      unsigned rw2 = pk_relu_add_f16(pv[i].z, er_pk[2], zero_pk);
      unsigned rw3 = pk_relu_add_f16(pv[i].w, er_pk[3], zero_pk);
      int bo = (row*512 + (t&31)*16) ^ ((row&7)<<4);
      *(uint4*)((char*)h1L + bo) = make_uint4(rw0,rw1,rw2,rw3);
    }
    BARRIER_LGKM();                          // A1
    // ---- P1b: build rows 32-63 (GEMM1-ph0 reads only rows 0-31: disjoint) ----
    #pragma unroll
    for (int i=2;i<4;i++){
      int row = (t>>5) + i*16;
      unsigned rw0 = pk_relu_add_f16(pv[i].x, er_pk[0], zero_pk);
      unsigned rw1 = pk_relu_add_f16(pv[i].y, er_pk[1], zero_pk);
      unsigned rw2 = pk_relu_add_f16(pv[i].z, er_pk[2], zero_pk);
      unsigned rw3 = pk_relu_add_f16(pv[i].w, er_pk[3], zero_pk);
      int bo = (row*512 + (t&31)*16) ^ ((row&7)<<4);
      *(uint4*)((char*)h1L + bo) = make_uint4(rw0,rw1,rw2,rw3);
    }
    // gathers for chunk c-1 (waves 2-7; consumed in P4) — stay in flight past barriers
    if (c > 0 && t >= 128){
      int tt = t - 128;
      int g0 = (c-1)*64;
      if (tt < 192) tmu  = muT [g0*3 + tt];
      if (tt < 384) tcov = covT[g0*6 + tt];
      if (tt < 64)  top  = opT [g0 + tt];
      if (tt < 384) tsh0 = shT [g0*9 + tt];
      if (tt < 192) tsh1 = shT [g0*9 + 384 + tt];
    }
    // prefetch next chunk's ptb — stays in flight past barriers
    {
      int p0n = p0 + 64;
      #pragma unroll
      for (int i=0;i<4;i++){
        int p = p0n + (t>>5) + i*16; p = (p>999)?999:p;
        pv[i] = *(const uint4*)(ptb + p*256 + (t&31)*8);
      }
    }
    // ---- P2a: GEMM1 ph0 (points 0-31): acc0 = W2slice x h1^T ----
    float16v acc0, acc1;
    #pragma unroll
    for (int r=0;r<16;r++){ acc0[r] = 0.f; acc1[r] = 0.f; }
    {
      int prx = (l32&7)<<4;
      int kb = hi*16;
      __builtin_amdgcn_s_setprio(1);
      #pragma unroll
      for (int s=0;s<16;s++){
        half8 b = *(const half8*)((char*)h1L + ((l32*512 + s*32 + kb) ^ prx));
        acc0 = __builtin_amdgcn_mfma_f32_32x32x16_f16(bB[s], b, acc0, 0,0,0);
      }
      __builtin_amdgcn_s_setprio(0);
    }
    BARRIER_LGKM();                          // A2: rows 32-63 written; ph0 reads done
    // ---- P2b: GEMM1 ph1 (points 32-63) ∥ WB0 (h2 lo -> h1L rows 0-31)
    //                                     ∥ WB1 (h2 hi -> h2H, disjoint: no barrier)
    {
      int pr = 32 + l32;
      int prx = (pr&7)<<4;
      int kb = hi*16;
      __builtin_amdgcn_s_setprio(1);
      #pragma unroll
      for (int s=0;s<16;s++){
        half8 b = *(const half8*)((char*)h1L + ((pr*512 + s*32 + kb) ^ prx));
        acc1 = __builtin_amdgcn_mfma_f32_32x32x16_f16(bB[s], b, acc1, 0,0,0);
      }
      __builtin_amdgcn_s_setprio(0);
    }
    {
      int p = l32;
      int rowx = (p&7)<<4;
      #pragma unroll
      for (int run=0; run<4; run++){
        int nb = wid*32 + run*8 + hi*4;
        float4v bz = *(float4v*)&b2L[nb];
        float v0 = fmaxf(acc0[run*4+0]+bz[0], 0.f);
        float v1 = fmaxf(acc0[run*4+1]+bz[1], 0.f);
        float v2 = fmaxf(acc0[run*4+2]+bz[2], 0.f);
        float v3 = fmaxf(acc0[run*4+3]+bz[3], 0.f);
        uint2 val; val.x = cvt_pk_f16(v0,v1); val.y = cvt_pk_f16(v2,v3);
        *(uint2*)((char*)h1L + ((p*512 + nb*2) ^ rowx)) = val;
      }
    }
    {
      int hr = l32;                          // h2H row = point-32
      int rowx = (hr&7)<<4;
      #pragma unroll
      for (int run=0; run<4; run++){
        int nb = wid*32 + run*8 + hi*4;
        float4v bz = *(float4v*)&b2L[nb];
        float v0 = fmaxf(acc1[run*4+0]+bz[0], 0.f);
        float v1 = fmaxf(acc1[run*4+1]+bz[1], 0.f);
        float v2 = fmaxf(acc1[run*4+2]+bz[2], 0.f);
        float v3 = fmaxf(acc1[run*4+3]+bz[3], 0.f);
        uint2 val; val.x = cvt_pk_f16(v0,v1); val.y = cvt_pk_f16(v2,v3);
        *(uint2*)((char*)h2H + ((hr*512 + nb*2) ^ rowx)) = val;
      }
    }
    BARRIER_LGKM();                          // C: all h2 (h1L rows 0-31 + h2H) complete
    // ---- P4: waves 0-1: GEMM2(c) -> pL[c&1]; waves 2-7: epilogue(c-1) ----
    if (wid < 2){
      float16v acc2;
      #pragma unroll
      for (int r=0;r<16;r++) acc2[r] = 0.f;
      const char* hbase = wid ? (const char*)h2H : (const char*)h1L;
      int jr = l32;
      int kb2 = hi * 16;
      int prx = (l32&7)<<4, jrx = (jr&7)<<4;
      __builtin_amdgcn_s_setprio(1);
      #pragma unroll
      for (int s=0;s<16;s++){
        int nb = s*32 + kb2;
        half8 a2 = *(const half8*)(hbase + ((l32*512 + nb) ^ prx));
        half8 bw = *(const half8*)((char*)w3L + ((jr*512 + nb) ^ jrx));
        acc2 = __builtin_amdgcn_mfma_f32_32x32x16_f16(a2, bw, acc2, 0,0,0);
      }
      __builtin_amdgcn_s_setprio(0);
      if (jr < 19){
        float bj = b3L[jr];
        int pb = wid*32 + 4*hi;
        #pragma unroll
        for (int r=0;r<16;r++){
          int p_out = pb + (r&3) + 8*(r>>2);
          pL[c&1][p_out][jr] = acc2[r] + bj;
        }
      }
    } else if (c > 0){
      int tt = t - 128;
      int par = (c-1)&1;
      int base = e*1000 + (c-1)*64;
      if (tt < 192){ int p=tt/3, q=tt-p*3; out[MU_OFF + base*3 + tt] = pL[par][p][q] + tmu; }
      if (tt < 384){ int p=tt/6, q=tt-p*6; out[COV_OFF + base*6 + tt] = pL[par][p][3+q] + tcov; }
      if (tt < 64){ float v = pL[par][tt][9]; out[OP_OFF + base + tt] = 1.f/(1.f+__expf(-v)) + top; }
      if (tt < 384){ int p=tt/9, q=tt-p*9; out[SH_OFF + base*9 + tt] = pL[par][p][10+q] + tsh0; }
      if (tt < 192){ int i2=tt+384; int p=i2/9, q=i2-p*9; out[SH_OFF + base*9 + i2] = pL[par][p][10+q] + tsh1; }
    }
    BARRIER_LGKM();                          // D: wave0 GEMM2 h1L reads done before next P1a
  }
  // ---- tail: epilogue for chunk 15 (valid=40), all threads, pL[1] ----
  {
    int base = e*1000 + 960;
    float gmu=0.f,gcov=0.f,gop=0.f,gsh=0.f;
    if (t < 120) gmu  = muT [2880 + t];
    if (t < 240) gcov = covT[5760 + t];
    if (t < 40)  gop  = opT [960 + t];
    if (t < 360) gsh  = shT [8640 + t];
    if (t < 120){ int p=t/3, q=t-p*3; out[MU_OFF + base*3 + t] = pL[1][p][q] + gmu; }
    if (t < 240){ int p=t/6, q=t-p*6; out[COV_OFF + base*6 + t] = pL[1][p][3+q] + gcov; }
    if (t < 40){ float v = pL[1][t][9]; out[OP_OFF + base + t] = 1.f/(1.f+__expf(-v)) + gop; }
    if (t < 360){ int p=t/9, q=t-p*9; out[SH_OFF + base*9 + t] = pL[1][p][10+q] + gsh; }
  }
}

extern "C" void kernel_launch(void* const* d_in, const int* in_sizes, int n_in,
                              void* d_out, int out_size, void* d_ws, size_t ws_size,
                              hipStream_t stream){
  const float* ef    = (const float*)d_in[0];
  const int*   cls   = (const int*)d_in[1];
  const int*   aid   = (const int*)d_in[2];
  const float* se_w1 = (const float*)d_in[3];
  const float* se_b1 = (const float*)d_in[4];
  const float* se_g  = (const float*)d_in[5];
  const float* se_be = (const float*)d_in[6];
  const float* se_w2 = (const float*)d_in[7];
  const float* se_b2 = (const float*)d_in[8];
  const float* cpts  = (const float*)d_in[9];
  const float* gw1   = (const float*)d_in[10];
  const float* gb1   = (const float*)d_in[11];
  const float* gw2   = (const float*)d_in[12];
  const float* gb2   = (const float*)d_in[13];
  const float* gw3   = (const float*)d_in[14];
  const float* gb3   = (const float*)d_in[15];
  const float* mu_t  = (const float*)d_in[16];
  const float* cov_t = (const float*)d_in[17];
  const float* op_t  = (const float*)d_in[18];
  const float* sh_t  = (const float*)d_in[19];
  float* out = (float*)d_out;
  char* ws = (char*)d_ws;
  unsigned short* w1b = (unsigned short*)(ws);                // 524288 B
  unsigned short* w2t = (unsigned short*)(ws + 524288);       // 131072 B
  unsigned short* w3p = (unsigned short*)(ws + 655360);       // 16384  B
  unsigned short* ptb = (unsigned short*)(ws + 671744);       // 512000 B

  kprep<<<2312, 256, 0, stream>>>(se_w1, gw2, gw3, gw1, cpts, w1b, w2t, w3p, ptb);
  kmain<<<512, 512, 0, stream>>>(ef, cls, w1b, se_b1, se_g, se_be, se_w2, se_b2,
                                 gw1, gb1, ptb, w2t, w3p, gb2, gb3, aid,
                                 mu_t, cov_t, op_t, sh_t, out);
}

// Round 14
// 128.268 us; speedup vs baseline: 1.0780x; 1.0780x over previous
//
#include <hip/hip_runtime.h>

typedef __attribute__((ext_vector_type(8))) short short8;
typedef __attribute__((ext_vector_type(8))) _Float16 half8;
typedef __attribute__((ext_vector_type(4))) float float4v;
typedef __attribute__((ext_vector_type(16))) float float16v;

#define SDIM 64

// output tensor offsets (floats)
#define MU_OFF   0
#define COV_OFF  1536000
#define OP_OFF   4608000
#define SH_OFF   5120000

// barrier with LDS-only drain: keeps global loads (prefetch/gathers) in flight
#define BARRIER_LGKM() asm volatile("s_waitcnt lgkmcnt(0)\n\ts_barrier" ::: "memory")

__device__ __forceinline__ unsigned short f2h(float f){
  _Float16 h = (_Float16)f;                 // v_cvt_f16_f32 (RNE)
  return *(unsigned short*)&h;
}
__device__ __forceinline__ float h2f(unsigned short u){
  _Float16 h = *(_Float16*)&u; return (float)h;
}
// packed fp16: r = max(p + e, 0)  (2 VALU ops per 2 elements)
__device__ __forceinline__ unsigned pk_relu_add_f16(unsigned p, unsigned e, unsigned z){
  unsigned r;
  asm("v_pk_add_f16 %0, %1, %2\n\tv_pk_max_f16 %0, %0, %3"
      : "=&v"(r) : "v"(p), "v"(e), "v"(z));
  return r;
}
// pack 2 f32 -> 2 f16 (RTZ), single instruction
__device__ __forceinline__ unsigned cvt_pk_f16(float lo, float hi){
  unsigned r; asm("v_cvt_pkrtz_f16_f32 %0, %1, %2" : "=v"(r) : "v"(lo), "v"(hi)); return r;
}

// ---------------- prep: fp16 conversions + pt_part ----------------
__global__ __launch_bounds__(256) void kprep(
    const float* __restrict__ se_w1, const float* __restrict__ gep_w2,
    const float* __restrict__ gep_w3, const float* __restrict__ gep_w1,
    const float* __restrict__ cpts,
    unsigned short* __restrict__ w1b, unsigned short* __restrict__ w2t,
    unsigned short* __restrict__ w3p, unsigned short* __restrict__ ptb){
  int idx = blockIdx.x*256 + threadIdx.x;
  if (idx < 262144){ w1b[idx] = f2h(se_w1[idx]); return; }
  int i1 = idx - 262144;
  if (i1 < 65536){ int n = i1 >> 8, k = i1 & 255; w2t[i1] = f2h(gep_w2[k*256+n]); return; }
  int i2 = idx - 327680;
  if (i2 < 8192){ int j = i2 >> 8, k = i2 & 255; w3p[i2] = f2h(j < 19 ? gep_w3[k*19+j] : 0.f); return; }
  int i3 = idx - 335872;
  if (i3 < 256000){ int p = i3 >> 8, k = i3 & 255;
    float v = cpts[p*3+0]*gep_w1[(SDIM+0)*256+k]
            + cpts[p*3+1]*gep_w1[(SDIM+1)*256+k]
            + cpts[p*3+2]*gep_w1[(SDIM+2)*256+k];
    ptb[i3] = f2h(v);
  }
}

// ---------------- main: fused entity prologue + per-entity point MLP via MFMA ----------------
// 512 threads = 8 waves; wave owns 32 GEMM1 cols. VGPR must stay <=128 for 2 blocks/CU.
// fp16 data path. 4 barriers/chunk: WB1 goes to a disjoint h2H buffer (no WAR with
// GEMM1-ph1's h1L reads). NO s_setprio: r13 showed it regresses (-10us) — all waves
// run the MFMA cluster in P2 (no arbitration target) and it starves P4's epilogue.
__global__ __launch_bounds__(512, 2) void kmain(
    const float* __restrict__ ef, const int* __restrict__ cls_lab,
    const unsigned short* __restrict__ w1b,
    const float* __restrict__ se_b1, const float* __restrict__ se_gamma,
    const float* __restrict__ se_beta, const float* __restrict__ se_w2,
    const float* __restrict__ se_b2,
    const float* __restrict__ gep_w1, const float* __restrict__ gep_b1,
    const unsigned short* __restrict__ ptb, const unsigned short* __restrict__ w2t,
    const unsigned short* __restrict__ w3p,
    const float* __restrict__ gep_b2, const float* __restrict__ gep_b3,
    const int* __restrict__ adapter_ids,
    const float* __restrict__ mu_tab, const float* __restrict__ cov_tab,
    const float* __restrict__ op_tab, const float* __restrict__ sh_tab,
    float* __restrict__ out){
  __shared__ unsigned short h1L[64*256];   // 32KB, XOR-swizzled rows of 512B (h1; rows 0-31 reused for h2 lo)
  __shared__ unsigned short h2H[32*256];   // 16KB, h2 rows 32-63 (disjoint from h1L -> no WAR barrier)
  __shared__ unsigned short w3L[32*256];   // 16KB (prologue: f32 scratch)
  __shared__ float entL[256];
  __shared__ float b2L[256];
  __shared__ float b3L[32];
  __shared__ float pL[2][64][21];          // double-buffered param staging
  int e = blockIdx.x, t = threadIdx.x;
  int lane = t & 63, wid = t >> 6;        // wid 0..7
  int l32 = lane & 31, hi = lane >> 5;

  // ================= fused entity prologue =================
  {
    float* efF = (float*)h1L;              // [0..1023] ef
    float* red = (float*)h1L + 1024;       // [16][256] matvec partials
    float* scr = (float*)w3L;              // [512..767] hr, [768..1279] styR,
                                           // [1280..1343] styL, [1344..1359] red8
    ((float2*)efF)[t] = ((const float2*)(ef + (size_t)e*1024))[t];
    if (t < 256) b2L[t] = gep_b2[t];
    if (t < 32) b3L[t] = (t < 19) ? gep_b3[t] : 0.f;
    __syncthreads();
    {
      int kg = t >> 5, c8 = (t & 31)*8;
      const unsigned short* wrow = w1b + (kg*64)*256 + c8;
      float a[8];
      #pragma unroll
      for (int j=0;j<8;j++) a[j]=0.f;
      #pragma unroll 8
      for (int k=0;k<64;k++){
        short8 w = *(const short8*)(wrow + k*256);
        float ev = efF[kg*64 + k];
        #pragma unroll
        for (int j=0;j<8;j++) a[j] += ev * h2f((unsigned short)w[j]);
      }
      #pragma unroll
      for (int j=0;j<8;j++) red[kg*256 + c8 + j] = a[j];
    }
    __syncthreads();
    float h = 0.f;
    if (t < 256){
      float s = 0.f;
      #pragma unroll
      for (int g=0; g<16; g++) s += red[g*256 + t];
      h = s + se_b1[t];
    }
    float s1 = h, s2 = h*h;
    #pragma unroll
    for (int o=32;o>0;o>>=1){ s1 += __shfl_xor(s1,o,64); s2 += __shfl_xor(s2,o,64); }
    if (lane==0){ scr[1344+wid]=s1; scr[1352+wid]=s2; }
    __syncthreads();
    float S1=0.f, S2=0.f;
    #pragma unroll
    for (int i=0;i<8;i++){ S1 += scr[1344+i]; S2 += scr[1352+i]; }
    float mean = S1*(1.f/256.f);
    float var  = S2*(1.f/256.f) - mean*mean;
    if (t < 256){
      float hn = (h-mean)*rsqrtf(var+1e-5f)*se_gamma[t] + se_beta[t];
      scr[512+t] = fmaxf(hn, 0.f);
    }
    __syncthreads();
    {
      int s = t & 63, q = t >> 6;
      float st = 0.f;
      #pragma unroll 4
      for (int k=q*32;k<q*32+32;k++) st += scr[512+k]*se_w2[k*64+s];
      scr[768 + q*64 + s] = st;
    }
    __syncthreads();
    if (t < 64){
      float v = 0.f;
      #pragma unroll
      for (int q=0;q<8;q++) v += scr[768 + q*64 + t];
      scr[1280+t] = v + se_b2[t];
    }
    __syncthreads();
    if (t < 256){
      int c = cls_lab[e];
      float ep = gep_b1[t] + gep_w1[(SDIM+3+c)*256 + t];
      #pragma unroll 8
      for (int k=0;k<64;k++) ep += scr[1280+k]*gep_w1[k*256+t];
      entL[t] = ep;
    }
    __syncthreads();                       // scr (w3L), h1L free from here
  }

  // stage W3 padded [32][256] f16 into LDS, swizzled
  #pragma unroll
  for (int i=0;i<2;i++){
    int g = t + i*512; int row = g>>5; int kg = g&31;
    uint4 v = *(const uint4*)(w3p + row*256 + kg*8);
    int bo = (row*512 + kg*16) ^ ((row&7)<<4);
    *(uint4*)((char*)w3L + bo) = v;
  }
  // persistent W2 fragments for 32x32x16 f16 GEMM1: 16 half8 = 64 VGPR
  half8 bB[16];
  #pragma unroll
  for (int s=0;s<16;s++)
    bB[s] = *(const half8*)(w2t + (wid*32 + l32)*256 + s*16 + hi*8);
  __syncthreads();

  int aid = adapter_ids[e];
  const float* muT  = mu_tab  + (size_t)aid*3000;
  const float* covT = cov_tab + (size_t)aid*6000;
  const float* opT  = op_tab  + (size_t)aid*1000;
  const float* shT  = sh_tab  + (size_t)aid*9000;
  int kg0 = (t & 31)*8;
  // ent packed to f16 pairs once (RNE)
  unsigned er_pk[4];
  #pragma unroll
  for (int j=0;j<4;j++)
    er_pk[j] = (unsigned)f2h(entL[kg0+2*j]) | ((unsigned)f2h(entL[kg0+2*j+1])<<16);
  unsigned zero_pk = 0;

  // initial ptb prefetch (chunk 0)
  uint4 pv[4];
  #pragma unroll
  for (int i=0;i<4;i++){
    int p = (t>>5) + i*16;
    pv[i] = *(const uint4*)(ptb + p*256 + (t&31)*8);
  }

  float tmu=0.f, tcov=0.f, top=0.f, tsh0=0.f, tsh1=0.f;   // gathers for chunk c-1

  for (int c=0;c<16;c++){
    int p0 = c*64;
    // ---- P1a: build h1 rows 0-31 (packed f16: 2 VALU per pair) ----
    #pragma unroll
    for (int i=0;i<2;i++){
      int row = (t>>5) + i*16;
      unsigned rw0 = pk_relu_add_f16(pv[i].x, er_pk[0], zero_pk);
      unsigned rw1 = pk_relu_add_f16(pv[i].y, er_pk[1], zero_pk);
      unsigned rw2 = pk_relu_add_f16(pv[i].z, er_pk[2], zero_pk);
      unsigned rw3 = pk_relu_add_f16(pv[i].w, er_pk[3], zero_pk);
      int bo = (row*512 + (t&31)*16) ^ ((row&7)<<4);
      *(uint4*)((char*)h1L + bo) = make_uint4(rw0,rw1,rw2,rw3);
    }
    BARRIER_LGKM();                          // A1
    // ---- P1b: build rows 32-63 (GEMM1-ph0 reads only rows 0-31: disjoint) ----
    #pragma unroll
    for (int i=2;i<4;i++){
      int row = (t>>5) + i*16;
      unsigned rw0 = pk_relu_add_f16(pv[i].x, er_pk[0], zero_pk);
      unsigned rw1 = pk_relu_add_f16(pv[i].y, er_pk[1], zero_pk);
      unsigned rw2 = pk_relu_add_f16(pv[i].z, er_pk[2], zero_pk);
      unsigned rw3 = pk_relu_add_f16(pv[i].w, er_pk[3], zero_pk);
      int bo = (row*512 + (t&31)*16) ^ ((row&7)<<4);
      *(uint4*)((char*)h1L + bo) = make_uint4(rw0,rw1,rw2,rw3);
    }
    // gathers for chunk c-1 (waves 2-7; consumed in P4) — stay in flight past barriers
    if (c > 0 && t >= 128){
      int tt = t - 128;
      int g0 = (c-1)*64;
      if (tt < 192) tmu  = muT [g0*3 + tt];
      if (tt < 384) tcov = covT[g0*6 + tt];
      if (tt < 64)  top  = opT [g0 + tt];
      if (tt < 384) tsh0 = shT [g0*9 + tt];
      if (tt < 192) tsh1 = shT [g0*9 + 384 + tt];
    }
    // prefetch next chunk's ptb — stays in flight past barriers
    {
      int p0n = p0 + 64;
      #pragma unroll
      for (int i=0;i<4;i++){
        int p = p0n + (t>>5) + i*16; p = (p>999)?999:p;
        pv[i] = *(const uint4*)(ptb + p*256 + (t&31)*8);
      }
    }
    // ---- P2a: GEMM1 ph0 (points 0-31): acc0 = W2slice x h1^T ----
    float16v acc0, acc1;
    #pragma unroll
    for (int r=0;r<16;r++){ acc0[r] = 0.f; acc1[r] = 0.f; }
    {
      int prx = (l32&7)<<4;
      int kb = hi*16;
      #pragma unroll
      for (int s=0;s<16;s++){
        half8 b = *(const half8*)((char*)h1L + ((l32*512 + s*32 + kb) ^ prx));
        acc0 = __builtin_amdgcn_mfma_f32_32x32x16_f16(bB[s], b, acc0, 0,0,0);
      }
    }
    BARRIER_LGKM();                          // A2: rows 32-63 written; ph0 reads done
    // ---- P2b: GEMM1 ph1 (points 32-63) ∥ WB0 (h2 lo -> h1L rows 0-31)
    //                                     ∥ WB1 (h2 hi -> h2H, disjoint: no barrier)
    {
      int pr = 32 + l32;
      int prx = (pr&7)<<4;
      int kb = hi*16;
      #pragma unroll
      for (int s=0;s<16;s++){
        half8 b = *(const half8*)((char*)h1L + ((pr*512 + s*32 + kb) ^ prx));
        acc1 = __builtin_amdgcn_mfma_f32_32x32x16_f16(bB[s], b, acc1, 0,0,0);
      }
    }
    {
      int p = l32;
      int rowx = (p&7)<<4;
      #pragma unroll
      for (int run=0; run<4; run++){
        int nb = wid*32 + run*8 + hi*4;
        float4v bz = *(float4v*)&b2L[nb];
        float v0 = fmaxf(acc0[run*4+0]+bz[0], 0.f);
        float v1 = fmaxf(acc0[run*4+1]+bz[1], 0.f);
        float v2 = fmaxf(acc0[run*4+2]+bz[2], 0.f);
        float v3 = fmaxf(acc0[run*4+3]+bz[3], 0.f);
        uint2 val; val.x = cvt_pk_f16(v0,v1); val.y = cvt_pk_f16(v2,v3);
        *(uint2*)((char*)h1L + ((p*512 + nb*2) ^ rowx)) = val;
      }
    }
    {
      int hr = l32;                          // h2H row = point-32
      int rowx = (hr&7)<<4;
      #pragma unroll
      for (int run=0; run<4; run++){
        int nb = wid*32 + run*8 + hi*4;
        float4v bz = *(float4v*)&b2L[nb];
        float v0 = fmaxf(acc1[run*4+0]+bz[0], 0.f);
        float v1 = fmaxf(acc1[run*4+1]+bz[1], 0.f);
        float v2 = fmaxf(acc1[run*4+2]+bz[2], 0.f);
        float v3 = fmaxf(acc1[run*4+3]+bz[3], 0.f);
        uint2 val; val.x = cvt_pk_f16(v0,v1); val.y = cvt_pk_f16(v2,v3);
        *(uint2*)((char*)h2H + ((hr*512 + nb*2) ^ rowx)) = val;
      }
    }
    BARRIER_LGKM();                          // C: all h2 (h1L rows 0-31 + h2H) complete
    // ---- P4: waves 0-1: GEMM2(c) -> pL[c&1]; waves 2-7: epilogue(c-1) ----
    if (wid < 2){
      float16v acc2;
      #pragma unroll
      for (int r=0;r<16;r++) acc2[r] = 0.f;
      const char* hbase = wid ? (const char*)h2H : (const char*)h1L;
      int jr = l32;
      int kb2 = hi * 16;
      int prx = (l32&7)<<4, jrx = (jr&7)<<4;
      #pragma unroll
      for (int s=0;s<16;s++){
        int nb = s*32 + kb2;
        half8 a2 = *(const half8*)(hbase + ((l32*512 + nb) ^ prx));
        half8 bw = *(const half8*)((char*)w3L + ((jr*512 + nb) ^ jrx));
        acc2 = __builtin_amdgcn_mfma_f32_32x32x16_f16(a2, bw, acc2, 0,0,0);
      }
      if (jr < 19){
        float bj = b3L[jr];
        int pb = wid*32 + 4*hi;
        #pragma unroll
        for (int r=0;r<16;r++){
          int p_out = pb + (r&3) + 8*(r>>2);
          pL[c&1][p_out][jr] = acc2[r] + bj;
        }
      }
    } else if (c > 0){
      int tt = t - 128;
      int par = (c-1)&1;
      int base = e*1000 + (c-1)*64;
      if (tt < 192){ int p=tt/3, q=tt-p*3; out[MU_OFF + base*3 + tt] = pL[par][p][q] + tmu; }
      if (tt < 384){ int p=tt/6, q=tt-p*6; out[COV_OFF + base*6 + tt] = pL[par][p][3+q] + tcov; }
      if (tt < 64){ float v = pL[par][tt][9]; out[OP_OFF + base + tt] = 1.f/(1.f+__expf(-v)) + top; }
      if (tt < 384){ int p=tt/9, q=tt-p*9; out[SH_OFF + base*9 + tt] = pL[par][p][10+q] + tsh0; }
      if (tt < 192){ int i2=tt+384; int p=i2/9, q=i2-p*9; out[SH_OFF + base*9 + i2] = pL[par][p][10+q] + tsh1; }
    }
    BARRIER_LGKM();                          // D: wave0 GEMM2 h1L reads done before next P1a
  }
  // ---- tail: epilogue for chunk 15 (valid=40), all threads, pL[1] ----
  {
    int base = e*1000 + 960;
    float gmu=0.f,gcov=0.f,gop=0.f,gsh=0.f;
    if (t < 120) gmu  = muT [2880 + t];
    if (t < 240) gcov = covT[5760 + t];
    if (t < 40)  gop  = opT [960 + t];
    if (t < 360) gsh  = shT [8640 + t];
    if (t < 120){ int p=t/3, q=t-p*3; out[MU_OFF + base*3 + t] = pL[1][p][q] + gmu; }
    if (t < 240){ int p=t/6, q=t-p*6; out[COV_OFF + base*6 + t] = pL[1][p][3+q] + gcov; }
    if (t < 40){ float v = pL[1][t][9]; out[OP_OFF + base + t] = 1.f/(1.f+__expf(-v)) + gop; }
    if (t < 360){ int p=t/9, q=t-p*9; out[SH_OFF + base*9 + t] = pL[1][p][10+q] + gsh; }
  }
}

extern "C" void kernel_launch(void* const* d_in, const int* in_sizes, int n_in,
                              void* d_out, int out_size, void* d_ws, size_t ws_size,
                              hipStream_t stream){
  const float* ef    = (const float*)d_in[0];
  const int*   cls   = (const int*)d_in[1];
  const int*   aid   = (const int*)d_in[2];
  const float* se_w1 = (const float*)d_in[3];
  const float* se_b1 = (const float*)d_in[4];
  const float* se_g  = (const float*)d_in[5];
  const float* se_be = (const float*)d_in[6];
  const float* se_w2 = (const float*)d_in[7];
  const float* se_b2 = (const float*)d_in[8];
  const float* cpts  = (const float*)d_in[9];
  const float* gw1   = (const float*)d_in[10];
  const float* gb1   = (const float*)d_in[11];
  const float* gw2   = (const float*)d_in[12];
  const float* gb2   = (const float*)d_in[13];
  const float* gw3   = (const float*)d_in[14];
  const float* gb3   = (const float*)d_in[15];
  const float* mu_t  = (const float*)d_in[16];
  const float* cov_t = (const float*)d_in[17];
  const float* op_t  = (const float*)d_in[18];
  const float* sh_t  = (const float*)d_in[19];
  float* out = (float*)d_out;
  char* ws = (char*)d_ws;
  unsigned short* w1b = (unsigned short*)(ws);                // 524288 B
  unsigned short* w2t = (unsigned short*)(ws + 524288);       // 131072 B
  unsigned short* w3p = (unsigned short*)(ws + 655360);       // 16384  B
  unsigned short* ptb = (unsigned short*)(ws + 671744);       // 512000 B

  kprep<<<2312, 256, 0, stream>>>(se_w1, gw2, gw3, gw1, cpts, w1b, w2t, w3p, ptb);
  kmain<<<512, 512, 0, stream>>>(ef, cls, w1b, se_b1, se_g, se_be, se_w2, se_b2,
                                 gw1, gb1, ptb, w2t, w3p, gb2, gb3, aid,
                                 mu_t, cov_t, op_t, sh_t, out);
}